// Round 7
// baseline (206.200 us; speedup 1.0000x reference)
//
#include <hip/hip_runtime.h>
#include <math.h>

// Problem constants: B=32 batches, N=64 points, D=64 hidden.
#define BB 32
#define NN 64
#define DD 64
constexpr int MAT = BB * NN * NN;              // one (B,N,N) f32 matrix = 131072 floats
// ws float-offset map:
//  0*MAT  A_ij  [b][i][j]   f32 (scaled by -0.125*log2e)
//  1*MAT  A_ik  [b][i][k]   f32
//  2*MAT  A_il  [b][i][l]   f32
//  3*MAT  A_jkT [b][k][j]   f32 (raw)
//  4*MAT  R_kl  [b][k][l]   f32 = exp2(A_kl)
//  5*MAT  E_jl  f16, 4-j-group interleaved [b][j>>2][l][j&3]  (65536 floats)
constexpr int E_OFF    = 5 * MAT;
constexpr int DJ_OFF   = E_OFF + MAT / 2;      // dj-pack f16: [b][i][jp][4 dwords]
constexpr int DJ_PER_B = 64 * 32 * 4;          // 8192 floats per batch
constexpr int PART_OFF = DJ_OFF + BB * DJ_PER_B; // per-block partials [2048]
constexpr int TICK_OFF = PART_OFF + BB * NN;   // ticket counter (int)

typedef _Float16 h2 __attribute__((ext_vector_type(2)));

static __device__ __forceinline__ h2 pkh(float a, float b) {
  return __builtin_bit_cast(h2, __builtin_amdgcn_cvt_pkrtz(a, b));
}
static __device__ __forceinline__ h2 bch(float f) {
  return __builtin_bit_cast(h2, f);
}
static __device__ __forceinline__ h2 rcp2h(h2 x) {
  h2 r;
  r.x = static_cast<_Float16>(__builtin_amdgcn_rcph(x.x));
  r.y = static_cast<_Float16>(__builtin_amdgcn_rcph(x.y));
  return r;
}

// ---------------------------------------------------------------------------
// Phase 1 (grid B*7): m=0..5 the six bilinear attention matrices via the 4x4
// augmented form  q_i.k_j = aug(p_i)^T (W_A W_B^T) aug(p_j).
// m4 (E_jl): log clamped to +-9 then exp2 -> f16 in [2^-9, 2^9]; 4-j-group
// interleave so the main loop reads 4 j's per ds_read_b64.
// m5 (R_kl): exp2() f32 (clamping happens later in f32).
// m6: f16 displacement pack + zero the last-block ticket.
// ---------------------------------------------------------------------------
__global__ __launch_bounds__(256) void simplex_phase1(
    const float* __restrict__ pc,
    const float* __restrict__ Wq,  const float* __restrict__ bq,
    const float* __restrict__ Wk1, const float* __restrict__ bk1,
    const float* __restrict__ Wk2, const float* __restrict__ bk2,
    const float* __restrict__ Wk3, const float* __restrict__ bk3,
    float* __restrict__ ws)
{
  const int blk = blockIdx.x;
  const int m   = blk % 7;
  const int b   = blk / 7;
  const int tid = threadIdx.x;

  __shared__ float M[4][4];
  __shared__ float P[NN][3];

  if (m < 6 && tid < 16) {
    int r = tid >> 2, c = tid & 3;
    const float *WA = Wq, *bA = bq, *WB = Wk1, *bB = bk1;
    switch (m) {
      case 0: WA = Wq;  bA = bq;  WB = Wk1; bB = bk1; break; // A_ij  (i,j)
      case 1: WA = Wq;  bA = bq;  WB = Wk2; bB = bk2; break; // A_ik  (i,k)
      case 2: WA = Wq;  bA = bq;  WB = Wk3; bB = bk3; break; // A_il  (i,l)
      case 3: WA = Wk2; bA = bk2; WB = Wk1; bB = bk1; break; // A_jkT (k,j)
      case 4: WA = Wk1; bA = bk1; WB = Wk3; bB = bk3; break; // E_jl  (j,l)
      case 5: WA = Wk2; bA = bk2; WB = Wk3; bB = bk3; break; // R_kl  (k,l)
    }
    float s = 0.f;
    for (int d = 0; d < DD; ++d) {
      float va = (r < 3) ? WA[r * DD + d] : bA[d];
      float vb = (c < 3) ? WB[c * DD + d] : bB[d];
      s = fmaf(va, vb, s);
    }
    M[r][c] = s;
  }
  if (tid < NN * 3) {
    ((float*)P)[tid] = pc[b * NN * 3 + tid];
  }
  __syncthreads();

  if (m == 6) {
    // dj-pack: [i][jp][4 dwords] = {h2{x0,x1}, h2{y0,y1}, h2{z0,z1}, 0}
    for (int idx = tid; idx < DJ_PER_B; idx += 256) {
      int w  = idx & 3;
      int jp = (idx >> 2) & 31;
      int i  = idx >> 7;
      float out = 0.f;
      if (w < 3) {
        float v0 = P[2 * jp + 0][w] - P[i][w];
        float v1 = P[2 * jp + 1][w] - P[i][w];
        out = __builtin_bit_cast(float, __builtin_amdgcn_cvt_pkrtz(v0, v1));
      }
      ws[DJ_OFF + b * DJ_PER_B + idx] = out;
    }
    if (b == 0 && tid == 0) ((int*)(ws + TICK_OFF))[0] = 0;  // zero ticket
    return;
  }

  const float scale2 = -0.125f * 1.4426950408889634f; // -scale*log2(e)

  for (int it = 0; it < 16; ++it) {
    int g = tid + 256 * it;        // 0..4095
    int r = g >> 6, c = g & 63;
    float ar0 = P[r][0], ar1 = P[r][1], ar2 = P[r][2];
    float ac0 = P[c][0], ac1 = P[c][1], ac2 = P[c][2];
    float t0 = fmaf(M[0][0], ac0, fmaf(M[0][1], ac1, fmaf(M[0][2], ac2, M[0][3])));
    float t1 = fmaf(M[1][0], ac0, fmaf(M[1][1], ac1, fmaf(M[1][2], ac2, M[1][3])));
    float t2 = fmaf(M[2][0], ac0, fmaf(M[2][1], ac1, fmaf(M[2][2], ac2, M[2][3])));
    float t3 = fmaf(M[3][0], ac0, fmaf(M[3][1], ac1, fmaf(M[3][2], ac2, M[3][3])));
    float v = fmaf(ar0, t0, fmaf(ar1, t1, fmaf(ar2, t2, t3))) * scale2;
    if (m == 4) {
      // clamp log to +-9 -> E in [2^-9, 2^9], f16-safe (no inf, no 0)
      float vc = fminf(fmaxf(v, -9.f), 9.f);
      _Float16 hv = (_Float16)__builtin_amdgcn_exp2f(vc);
      // 4-j-group interleave: idx = (j>>2)*256 + l*4 + (j&3)   (j=r, l=c)
      ((_Float16*)(ws + E_OFF))[b * 4096 + ((r >> 2) << 8) + (c << 2) + (r & 3)] = hv;
    } else if (m == 5) {
      ws[4 * MAT + b * 4096 + g] = __builtin_amdgcn_exp2f(v);
    } else {
      ws[m * MAT + b * 4096 + g] = v;
    }
  }
}

// ---------------------------------------------------------------------------
// Main kernel: one block per (b, anchor i). LANE = l; j in groups of 4;
// waves split k (2-k unroll). All eval math packed f16 with clamped factors:
//   T,E,M in [2^-9, 2^9];  e = min(E*M, 8192)  (pk_min kills any inf)
//   x = fma(T, e, 1)  in [1, +inf];  g = rcp_f16(x)  (inf -> 0, never NaN)
//   det = d_j . (d_k x d_l) pk f16;  acc = fdot2(g01, det^2, acc)  f32
// Last block (ticket) reduces the 2048 partials and runs the output MLP.
// ---------------------------------------------------------------------------
__global__ __launch_bounds__(256, 8) void simplex_main(
    const float* __restrict__ pc,
    const float* __restrict__ ws_in,
    float* __restrict__ ws_rw,
    const float* __restrict__ W1, const float* __restrict__ b1,
    const float* __restrict__ W2, const float* __restrict__ b2,
    float* __restrict__ out)
{
  const int b    = blockIdx.x >> 6;
  const int i    = blockIdx.x & 63;
  const int tid  = threadIdx.x;
  const int lane = tid & 63;
  const int wu   = __builtin_amdgcn_readfirstlane(tid >> 6);

  __shared__ __align__(16) _Float16 sE[4096];    // [j>>2][l][j&3] (8 KB)
  __shared__ __align__(16) _Float16 sT[4][128];  // per wave: [t][j] f16
  __shared__ float dX[NN], dY[NN], dZ[NN];
  __shared__ float wsum[4];
  __shared__ int lastFlag;

  const float* m0  = ws_in + 0 * MAT + (b * 64 + i) * 64; // A_ij[j]
  const float* m1  = ws_in + 1 * MAT + (b * 64 + i) * 64; // A_ik[k]
  const float* m2  = ws_in + 2 * MAT + (b * 64 + i) * 64; // A_il[l]
  const float* m3  = ws_in + 3 * MAT + b * 4096;          // A_jkT[k][j]
  const float* m5R = ws_in + 4 * MAT + b * 4096;          // exp2(A_kl)[k][l]
  const float* Eg  = ws_in + E_OFF + b * 2048;            // E f16 (as floats)
  const float* djp = ws_in + DJ_OFF + b * DJ_PER_B + i * 128; // [jp][4]

  // stage E (8 KB) + displacements
  {
    const float4* src = (const float4*)Eg;
    float4* dst = (float4*)sE;
    dst[tid]       = src[tid];
    dst[tid + 256] = src[tid + 256];
  }
  if (tid < 64) {
    const float pix = pc[(b * 64 + i) * 3 + 0];
    const float piy = pc[(b * 64 + i) * 3 + 1];
    const float piz = pc[(b * 64 + i) * 3 + 2];
    dX[tid] = pc[(b * 64 + tid) * 3 + 0] - pix;
    dY[tid] = pc[(b * 64 + tid) * 3 + 1] - piy;
    dZ[tid] = pc[(b * 64 + tid) * 3 + 2] - piz;
  }
  __syncthreads();

  const float dlx = dX[lane], dly = dY[lane], dlz = dZ[lane];
  const float wl  = __builtin_amdgcn_exp2f(m2[lane]); // exp2(A_il[l]) per-lane
  const float aij = m0[lane];                          // lane plays j for T rows
  _Float16* sTw = &sT[wu][0];
  const h2 clampE = {(_Float16)8192.f, (_Float16)8192.f};
  float acc = 0.f;

  for (int n = 0; n < 8; ++n) {
    const int kk = __builtin_amdgcn_readfirstlane(n * 8 + 2 * wu);
    h2 cxh[2], cyh[2], czh[2], mmh[2];
#pragma unroll
    for (int t = 0; t < 2; ++t) {
      const int k = kk + t;
      const float dkx = dX[k], dky = dY[k], dkz = dZ[k];   // broadcast
      const float cx = dky * dlz - dkz * dly;              // d_k x d_l (per-lane)
      const float cy = dkz * dlx - dkx * dlz;
      const float cz = dkx * dly - dky * dlx;
      cxh[t] = pkh(cx, cx);
      cyh[t] = pkh(cy, cy);
      czh[t] = pkh(cz, cz);
      // M = R_kl * exp2(A_il), clamped to [2^-9, 2^9] in f32 (no inf/0 in f16)
      float mv = m5R[k * 64 + lane] * wl;
      mv = fminf(fmaxf(mv, 0.001953125f), 512.f);
      mmh[t] = pkh(mv, mv);
      // T = exp2(clamp(log,.)) in [2^-9, 2^9]
      float logT = aij + m3[k * 64 + lane] + m1[k];
      logT = fminf(fmaxf(logT, -9.f), 9.f);
      sTw[t * 64 + lane] = (_Float16)__builtin_amdgcn_exp2f(logT);
    }
    // same-wave LDS write->read: compiler inserts lgkmcnt wait; no barrier.
#pragma unroll 8
    for (int jg = 0; jg < 16; ++jg) {          // 4 j's per iteration
      const float2 Ef = ((const float2*)sE)[jg * 64 + lane];  // ds_read_b64
      const h2 Ea = bch(Ef.x);                 // E[j0],E[j1] at this l
      const h2 Eb = bch(Ef.y);                 // E[j2],E[j3]
      const float2 T0f = ((const float2*)sTw)[jg];        // t=0: T[j0..j3]
      const float2 T1f = ((const float2*)sTw)[16 + jg];   // t=1
      const float4 dj0 = *(const float4*)(djp + (2 * jg + 0) * 4); // s_load
      const float4 dj1 = *(const float4*)(djp + (2 * jg + 1) * 4);
      const h2 xx0 = bch(dj0.x), yy0 = bch(dj0.y), zz0 = bch(dj0.z);
      const h2 xx1 = bch(dj1.x), yy1 = bch(dj1.y), zz1 = bch(dj1.z);
#pragma unroll
      for (int t = 0; t < 2; ++t) {
        const float2 Tf = t ? T1f : T0f;
        const h2 Ta = bch(Tf.x), Tb = bch(Tf.y);
        // half a: j0,j1
        {
          h2 e = __builtin_elementwise_min(Ea * mmh[t], clampE);
          h2 x = __builtin_elementwise_fma(Ta, e,
                   (h2){(_Float16)1.0f, (_Float16)1.0f});
          h2 g = rcp2h(x);
          h2 det = __builtin_elementwise_fma(xx0, cxh[t],
                     __builtin_elementwise_fma(yy0, cyh[t], zz0 * czh[t]));
          acc = __builtin_amdgcn_fdot2(g, det * det, acc, false);
        }
        // half b: j2,j3
        {
          h2 e = __builtin_elementwise_min(Eb * mmh[t], clampE);
          h2 x = __builtin_elementwise_fma(Tb, e,
                   (h2){(_Float16)1.0f, (_Float16)1.0f});
          h2 g = rcp2h(x);
          h2 det = __builtin_elementwise_fma(xx1, cxh[t],
                     __builtin_elementwise_fma(yy1, cyh[t], zz1 * czh[t]));
          acc = __builtin_amdgcn_fdot2(g, det * det, acc, false);
        }
      }
    }
  }

  // lanes sum over l; waves over k slices -> per-block partial
  for (int s = 32; s; s >>= 1) acc += __shfl_xor(acc, s, 64);
  if (lane == 0) wsum[wu] = acc;
  __syncthreads();
  if (tid == 0) {
    float blocksum = wsum[0] + wsum[1] + wsum[2] + wsum[3];
    ws_rw[PART_OFF + blockIdx.x] = blocksum;
    __threadfence();                                        // release partial
    int old = atomicAdd((int*)(ws_rw + TICK_OFF), 1);
    lastFlag = (old == (BB * NN - 1));
  }
  __syncthreads();

  if (lastFlag) {
    __threadfence();
    if (tid < BB) {
      // reduce this batch's 64 partials (agent-scope loads bypass stale L1)
      float s = 0.f;
      for (int ii = 0; ii < 64; ++ii)
        s += __hip_atomic_load(ws_rw + PART_OFF + tid * 64 + ii,
                               __ATOMIC_RELAXED, __HIP_MEMORY_SCOPE_AGENT);
      float x = s * (1.f / 16777216.f);   // / N^4
      // gelu-tanh MLP
      float o = b2[0];
      for (int c = 0; c < 32; ++c) {
        float z  = fmaf(x, W1[c], b1[c]);
        float z3 = z * z * z;
        float y  = 0.7978845608028654f * fmaf(0.044715f, z3, z);
        float ay = fabsf(y);
        float e  = __builtin_amdgcn_exp2f(2.8853900817779268f * ay);
        float th = 1.f - 2.f / (e + 1.f);
        th = copysignf(th, y);
        float gl = 0.5f * z * (1.f + th);
        o = fmaf(gl, W2[c], o);
      }
      out[tid] = o;
    }
  }
}

// ---------------------------------------------------------------------------
extern "C" void kernel_launch(void* const* d_in, const int* in_sizes, int n_in,
                              void* d_out, int out_size, void* d_ws, size_t ws_size,
                              hipStream_t stream) {
  (void)in_sizes; (void)n_in; (void)out_size; (void)ws_size;
  const float* pc  = (const float*)d_in[0];
  const float* Wq  = (const float*)d_in[1];
  const float* bq  = (const float*)d_in[2];
  const float* Wk1 = (const float*)d_in[3];
  const float* bk1 = (const float*)d_in[4];
  const float* Wk2 = (const float*)d_in[5];
  const float* bk2 = (const float*)d_in[6];
  const float* Wk3 = (const float*)d_in[7];
  const float* bk3 = (const float*)d_in[8];
  const float* W1  = (const float*)d_in[9];
  const float* b1  = (const float*)d_in[10];
  const float* W2  = (const float*)d_in[11];
  const float* b2  = (const float*)d_in[12];

  float* ws  = (float*)d_ws;
  float* out = (float*)d_out;

  hipLaunchKernelGGL(simplex_phase1, dim3(BB * 7), dim3(256), 0, stream,
                     pc, Wq, bq, Wk1, bk1, Wk2, bk2, Wk3, bk3, ws);
  hipLaunchKernelGGL(simplex_main, dim3(BB * NN), dim3(256), 0, stream,
                     pc, ws, ws, W1, b1, W2, b2, out);
}

// Round 8
// 204.507 us; speedup vs baseline: 1.0083x; 1.0083x over previous
//
#include <hip/hip_runtime.h>
#include <math.h>

// Problem constants: B=32 batches, N=64 points, D=64 hidden.
#define BB 32
#define NN 64
#define DD 64
constexpr int MAT = BB * NN * NN;              // one (B,N,N) f32 matrix = 131072 floats
// ws float-offset map:
//  0*MAT  A_ij  [b][i][j]   f32 (scaled by -0.125*log2e)
//  1*MAT  A_ik  [b][i][k]   f32
//  2*MAT  A_il  [b][i][l]   f32
//  3*MAT  A_jkT [b][k][j]   f32 (raw)
//  4*MAT  R_kl  [b][k][l]   f32 = exp2(A_kl)
//  5*MAT  E_jl  f16, 4-j-group interleaved [b][j>>2][l][j&3]  (65536 floats)
constexpr int E_OFF    = 5 * MAT;
constexpr int DJ_OFF   = E_OFF + MAT / 2;      // dj-pack f16: [b][i][jp][4 dwords]
constexpr int DJ_PER_B = 64 * 32 * 4;          // 8192 floats per batch
constexpr int PART_OFF = DJ_OFF + BB * DJ_PER_B; // per-block partials [2048]
constexpr int TICK_OFF = PART_OFF + BB * NN;   // ticket counter (int)

typedef _Float16 h2 __attribute__((ext_vector_type(2)));

static __device__ __forceinline__ h2 pkh(float a, float b) {
  return __builtin_bit_cast(h2, __builtin_amdgcn_cvt_pkrtz(a, b));
}
static __device__ __forceinline__ h2 bch(float f) {
  return __builtin_bit_cast(h2, f);
}

// ---------------------------------------------------------------------------
// Phase 1 (grid B*7): m=0..5 the six bilinear attention matrices via the 4x4
// augmented form  q_i.k_j = aug(p_i)^T (W_A W_B^T) aug(p_j).
// m4 (E_jl): log clamped to +-9 then exp2 -> f16 in [2^-9, 2^9]; 4-j-group
// interleave so the main loop reads 4 j's per ds_read_b64.
// m5 (R_kl): exp2() f32 (clamping happens later in f32).
// m6: f16 displacement pack + zero the last-block ticket.
// ---------------------------------------------------------------------------
__global__ __launch_bounds__(256) void simplex_phase1(
    const float* __restrict__ pc,
    const float* __restrict__ Wq,  const float* __restrict__ bq,
    const float* __restrict__ Wk1, const float* __restrict__ bk1,
    const float* __restrict__ Wk2, const float* __restrict__ bk2,
    const float* __restrict__ Wk3, const float* __restrict__ bk3,
    float* __restrict__ ws)
{
  const int blk = blockIdx.x;
  const int m   = blk % 7;
  const int b   = blk / 7;
  const int tid = threadIdx.x;

  __shared__ float M[4][4];
  __shared__ float P[NN][3];

  if (m < 6 && tid < 16) {
    int r = tid >> 2, c = tid & 3;
    const float *WA = Wq, *bA = bq, *WB = Wk1, *bB = bk1;
    switch (m) {
      case 0: WA = Wq;  bA = bq;  WB = Wk1; bB = bk1; break; // A_ij  (i,j)
      case 1: WA = Wq;  bA = bq;  WB = Wk2; bB = bk2; break; // A_ik  (i,k)
      case 2: WA = Wq;  bA = bq;  WB = Wk3; bB = bk3; break; // A_il  (i,l)
      case 3: WA = Wk2; bA = bk2; WB = Wk1; bB = bk1; break; // A_jkT (k,j)
      case 4: WA = Wk1; bA = bk1; WB = Wk3; bB = bk3; break; // E_jl  (j,l)
      case 5: WA = Wk2; bA = bk2; WB = Wk3; bB = bk3; break; // R_kl  (k,l)
    }
    float s = 0.f;
    for (int d = 0; d < DD; ++d) {
      float va = (r < 3) ? WA[r * DD + d] : bA[d];
      float vb = (c < 3) ? WB[c * DD + d] : bB[d];
      s = fmaf(va, vb, s);
    }
    M[r][c] = s;
  }
  if (tid < NN * 3) {
    ((float*)P)[tid] = pc[b * NN * 3 + tid];
  }
  __syncthreads();

  if (m == 6) {
    // dj-pack: [i][jp][4 dwords] = {h2{x0,x1}, h2{y0,y1}, h2{z0,z1}, 0}
    for (int idx = tid; idx < DJ_PER_B; idx += 256) {
      int w  = idx & 3;
      int jp = (idx >> 2) & 31;
      int i  = idx >> 7;
      float out = 0.f;
      if (w < 3) {
        float v0 = P[2 * jp + 0][w] - P[i][w];
        float v1 = P[2 * jp + 1][w] - P[i][w];
        out = __builtin_bit_cast(float, __builtin_amdgcn_cvt_pkrtz(v0, v1));
      }
      ws[DJ_OFF + b * DJ_PER_B + idx] = out;
    }
    if (b == 0 && tid == 0) ((int*)(ws + TICK_OFF))[0] = 0;  // zero ticket
    return;
  }

  const float scale2 = -0.125f * 1.4426950408889634f; // -scale*log2(e)

  for (int it = 0; it < 16; ++it) {
    int g = tid + 256 * it;        // 0..4095
    int r = g >> 6, c = g & 63;
    float ar0 = P[r][0], ar1 = P[r][1], ar2 = P[r][2];
    float ac0 = P[c][0], ac1 = P[c][1], ac2 = P[c][2];
    float t0 = fmaf(M[0][0], ac0, fmaf(M[0][1], ac1, fmaf(M[0][2], ac2, M[0][3])));
    float t1 = fmaf(M[1][0], ac0, fmaf(M[1][1], ac1, fmaf(M[1][2], ac2, M[1][3])));
    float t2 = fmaf(M[2][0], ac0, fmaf(M[2][1], ac1, fmaf(M[2][2], ac2, M[2][3])));
    float t3 = fmaf(M[3][0], ac0, fmaf(M[3][1], ac1, fmaf(M[3][2], ac2, M[3][3])));
    float v = fmaf(ar0, t0, fmaf(ar1, t1, fmaf(ar2, t2, t3))) * scale2;
    if (m == 4) {
      // clamp log to +-9 -> E in [2^-9, 2^9], f16-safe (no inf, no 0)
      float vc = fminf(fmaxf(v, -9.f), 9.f);
      _Float16 hv = (_Float16)__builtin_amdgcn_exp2f(vc);
      // 4-j-group interleave: idx = (j>>2)*256 + l*4 + (j&3)   (j=r, l=c)
      ((_Float16*)(ws + E_OFF))[b * 4096 + ((r >> 2) << 8) + (c << 2) + (r & 3)] = hv;
    } else if (m == 5) {
      ws[4 * MAT + b * 4096 + g] = __builtin_amdgcn_exp2f(v);
    } else {
      ws[m * MAT + b * 4096 + g] = v;
    }
  }
}

// ---------------------------------------------------------------------------
// Main kernel: one block per (b, anchor i). LANE = l; j in groups of 4;
// waves split k (2-k unroll). Packed-f16 eval with ONE rcp per f16 pair:
//   x  = min(fma(T, E*M, 1), 255)          (x=inf -> 255; gate err <= 1/255
//                                           only on the sigma<0.004 tail)
//   rd = rcp_f16(x0*x1)                    (den <= 65025, no overflow)
//   acc = fdot2(d2*{rd,rd}, swap(x), acc)  (d0^2/x0 + d1^2/x1, f32 accum;
//                                           the x255 product lives in fdot2's
//                                           internal f32 math - no f16 inf)
// Last block (ticket) reduces the 2048 partials and runs the output MLP.
// ---------------------------------------------------------------------------
__global__ __launch_bounds__(256, 8) void simplex_main(
    const float* __restrict__ pc,
    const float* __restrict__ ws_in,
    float* __restrict__ ws_rw,
    const float* __restrict__ W1, const float* __restrict__ b1,
    const float* __restrict__ W2, const float* __restrict__ b2,
    float* __restrict__ out)
{
  const int b    = blockIdx.x >> 6;
  const int i    = blockIdx.x & 63;
  const int tid  = threadIdx.x;
  const int lane = tid & 63;
  const int wu   = __builtin_amdgcn_readfirstlane(tid >> 6);

  __shared__ __align__(16) _Float16 sE[4096];    // [j>>2][l][j&3] (8 KB)
  __shared__ __align__(16) _Float16 sT[4][128];  // per wave: [t][j] f16
  __shared__ float dX[NN], dY[NN], dZ[NN];
  __shared__ float wsum[4];
  __shared__ int lastFlag;

  const float* m0  = ws_in + 0 * MAT + (b * 64 + i) * 64; // A_ij[j]
  const float* m1  = ws_in + 1 * MAT + (b * 64 + i) * 64; // A_ik[k]
  const float* m2  = ws_in + 2 * MAT + (b * 64 + i) * 64; // A_il[l]
  const float* m3  = ws_in + 3 * MAT + b * 4096;          // A_jkT[k][j]
  const float* m5R = ws_in + 4 * MAT + b * 4096;          // exp2(A_kl)[k][l]
  const float* Eg  = ws_in + E_OFF + b * 2048;            // E f16 (as floats)
  const float* djp = ws_in + DJ_OFF + b * DJ_PER_B + i * 128; // [jp][4]

  // stage E (8 KB) + displacements
  {
    const float4* src = (const float4*)Eg;
    float4* dst = (float4*)sE;
    dst[tid]       = src[tid];
    dst[tid + 256] = src[tid + 256];
  }
  if (tid < 64) {
    const float pix = pc[(b * 64 + i) * 3 + 0];
    const float piy = pc[(b * 64 + i) * 3 + 1];
    const float piz = pc[(b * 64 + i) * 3 + 2];
    dX[tid] = pc[(b * 64 + tid) * 3 + 0] - pix;
    dY[tid] = pc[(b * 64 + tid) * 3 + 1] - piy;
    dZ[tid] = pc[(b * 64 + tid) * 3 + 2] - piz;
  }
  __syncthreads();

  const float dlx = dX[lane], dly = dY[lane], dlz = dZ[lane];
  const float wl  = __builtin_amdgcn_exp2f(m2[lane]); // exp2(A_il[l]) per-lane
  const float aij = m0[lane];                          // lane plays j for T rows
  _Float16* sTw = &sT[wu][0];
  const h2 c255 = bch(__builtin_bit_cast(float, 0x5BF85BF8u)); // {255,255}
  const h2 one  = bch(__builtin_bit_cast(float, 0x3C003C00u)); // {1,1}
  float acc = 0.f;

  for (int n = 0; n < 8; ++n) {
    const int kk = __builtin_amdgcn_readfirstlane(n * 8 + 2 * wu);
    h2 cxh[2], cyh[2], czh[2], mmh[2];
#pragma unroll
    for (int t = 0; t < 2; ++t) {
      const int k = kk + t;
      const float dkx = dX[k], dky = dY[k], dkz = dZ[k];   // broadcast
      const float cx = dky * dlz - dkz * dly;              // d_k x d_l (per-lane)
      const float cy = dkz * dlx - dkx * dlz;
      const float cz = dkx * dly - dky * dlx;
      cxh[t] = pkh(cx, cx);
      cyh[t] = pkh(cy, cy);
      czh[t] = pkh(cz, cz);
      // M = R_kl * exp2(A_il), clamped to [2^-9, 2^9] in f32 (no inf/0 in f16)
      float mv = m5R[k * 64 + lane] * wl;
      mv = fminf(fmaxf(mv, 0.001953125f), 512.f);
      mmh[t] = pkh(mv, mv);
      // T = exp2(clamp(log,.)) in [2^-9, 2^9]
      float logT = aij + m3[k * 64 + lane] + m1[k];
      logT = fminf(fmaxf(logT, -9.f), 9.f);
      sTw[t * 64 + lane] = (_Float16)__builtin_amdgcn_exp2f(logT);
    }
    // same-wave LDS write->read: compiler inserts lgkmcnt wait; no barrier.
#pragma unroll 8
    for (int jg = 0; jg < 16; ++jg) {          // 4 j's per iteration
      const float2 Ef = ((const float2*)sE)[jg * 64 + lane];  // ds_read_b64
      const h2 Ea = bch(Ef.x);                 // E[j0],E[j1] at this l
      const h2 Eb = bch(Ef.y);                 // E[j2],E[j3]
      const float2 T0f = ((const float2*)sTw)[jg];        // t=0: T[j0..j3]
      const float2 T1f = ((const float2*)sTw)[16 + jg];   // t=1
      const float4 dj0 = *(const float4*)(djp + (2 * jg + 0) * 4); // s_load
      const float4 dj1 = *(const float4*)(djp + (2 * jg + 1) * 4);
      const h2 xx0 = bch(dj0.x), yy0 = bch(dj0.y), zz0 = bch(dj0.z);
      const h2 xx1 = bch(dj1.x), yy1 = bch(dj1.y), zz1 = bch(dj1.z);
#pragma unroll
      for (int t = 0; t < 2; ++t) {
        const float2 Tf = t ? T1f : T0f;
        const h2 Ta = bch(Tf.x), Tb = bch(Tf.y);
        // half a: j0,j1
        {
          h2 x = __builtin_elementwise_fma(Ta, Ea * mmh[t], one);
          h2 xc = __builtin_elementwise_min(x, c255);
          _Float16 rd = static_cast<_Float16>(
              __builtin_amdgcn_rcph(xc.x * xc.y));
          h2 rd2; rd2.x = rd; rd2.y = rd;
          h2 xs = __builtin_shufflevector(xc, xc, 1, 0);
          h2 det = __builtin_elementwise_fma(xx0, cxh[t],
                     __builtin_elementwise_fma(yy0, cyh[t], zz0 * czh[t]));
          acc = __builtin_amdgcn_fdot2((det * det) * rd2, xs, acc, false);
        }
        // half b: j2,j3
        {
          h2 x = __builtin_elementwise_fma(Tb, Eb * mmh[t], one);
          h2 xc = __builtin_elementwise_min(x, c255);
          _Float16 rd = static_cast<_Float16>(
              __builtin_amdgcn_rcph(xc.x * xc.y));
          h2 rd2; rd2.x = rd; rd2.y = rd;
          h2 xs = __builtin_shufflevector(xc, xc, 1, 0);
          h2 det = __builtin_elementwise_fma(xx1, cxh[t],
                     __builtin_elementwise_fma(yy1, cyh[t], zz1 * czh[t]));
          acc = __builtin_amdgcn_fdot2((det * det) * rd2, xs, acc, false);
        }
      }
    }
  }

  // lanes sum over l; waves over k slices -> per-block partial
  for (int s = 32; s; s >>= 1) acc += __shfl_xor(acc, s, 64);
  if (lane == 0) wsum[wu] = acc;
  __syncthreads();
  if (tid == 0) {
    float blocksum = wsum[0] + wsum[1] + wsum[2] + wsum[3];
    ws_rw[PART_OFF + blockIdx.x] = blocksum;
    __threadfence();                                        // release partial
    int old = atomicAdd((int*)(ws_rw + TICK_OFF), 1);
    lastFlag = (old == (BB * NN - 1));
  }
  __syncthreads();

  if (lastFlag) {
    __threadfence();
    if (tid < BB) {
      // reduce this batch's 64 partials (agent-scope loads bypass stale L1)
      float s = 0.f;
      for (int ii = 0; ii < 64; ++ii)
        s += __hip_atomic_load(ws_rw + PART_OFF + tid * 64 + ii,
                               __ATOMIC_RELAXED, __HIP_MEMORY_SCOPE_AGENT);
      float x = s * (1.f / 16777216.f);   // / N^4
      // gelu-tanh MLP
      float o = b2[0];
      for (int c = 0; c < 32; ++c) {
        float z  = fmaf(x, W1[c], b1[c]);
        float z3 = z * z * z;
        float y  = 0.7978845608028654f * fmaf(0.044715f, z3, z);
        float ay = fabsf(y);
        float e  = __builtin_amdgcn_exp2f(2.8853900817779268f * ay);
        float th = 1.f - 2.f / (e + 1.f);
        th = copysignf(th, y);
        float gl = 0.5f * z * (1.f + th);
        o = fmaf(gl, W2[c], o);
      }
      out[tid] = o;
    }
  }
}

// ---------------------------------------------------------------------------
extern "C" void kernel_launch(void* const* d_in, const int* in_sizes, int n_in,
                              void* d_out, int out_size, void* d_ws, size_t ws_size,
                              hipStream_t stream) {
  (void)in_sizes; (void)n_in; (void)out_size; (void)ws_size;
  const float* pc  = (const float*)d_in[0];
  const float* Wq  = (const float*)d_in[1];
  const float* bq  = (const float*)d_in[2];
  const float* Wk1 = (const float*)d_in[3];
  const float* bk1 = (const float*)d_in[4];
  const float* Wk2 = (const float*)d_in[5];
  const float* bk2 = (const float*)d_in[6];
  const float* Wk3 = (const float*)d_in[7];
  const float* bk3 = (const float*)d_in[8];
  const float* W1  = (const float*)d_in[9];
  const float* b1  = (const float*)d_in[10];
  const float* W2  = (const float*)d_in[11];
  const float* b2  = (const float*)d_in[12];

  float* ws  = (float*)d_ws;
  float* out = (float*)d_out;

  hipLaunchKernelGGL(simplex_phase1, dim3(BB * 7), dim3(256), 0, stream,
                     pc, Wq, bq, Wk1, bk1, Wk2, bk2, Wk3, bk3, ws);
  hipLaunchKernelGGL(simplex_main, dim3(BB * NN), dim3(256), 0, stream,
                     pc, ws, ws, W1, b1, W2, b2, out);
}